// Round 16
// baseline (112.073 us; speedup 1.0000x reference)
//
#include <hip/hip_runtime.h>
#include <hip/hip_bf16.h>
#include <math.h>

// Collapsed math (softmax over the size-1 summary axis == 1 identically, so
// q/Wq/Wk/bias-MLP/mask-bias are dead code):
//   summary[bn,:] = sum_t m*x / max(sum_t m, 1e-6)
//   v[bn,:]       = summary @ Wv + bv
//   rf[bn,t]      = [dx,dy,dz,||d||,||d||^2] vs masked-mean position
//   rel_val       = gelu(rf @ Vw1 + Vb1) @ Vw2 + Vb2   (bf16 MFMA)
//   out[bn,t,:]   = x[bn,t,:] + v[bn,:] + rel_val[bn,t,:]
//
// Round-16: r15 (87.9us) lessons: ILP-rich wfr[4] batch is mandatory; regs
// must fit the wave band. Now raise k_fused occupancy 5->6 waves/SIMD while
// keeping ILP: two m-passes with acc[1][4] (16 AGPR live), tile rows written
// right after each pass. s_hid/s_tile separate regions (25KB -> 6 blocks/CU);
// budget 512/6=85 >= live ~70 -> no spill.

#define BN_TOT 512
#define T_DIM 256
#define D_DIM 256
#define HID 128

typedef __attribute__((ext_vector_type(8))) short short8v;
typedef __attribute__((ext_vector_type(4))) float f32x4;

static __device__ __forceinline__ ushort f2bf(float f) {
    __hip_bfloat16 h = __float2bfloat16(f);
    return *reinterpret_cast<ushort*>(&h);
}
static __device__ __forceinline__ float bf2f(ushort u) {
    uint v = ((uint)u) << 16;
    return *reinterpret_cast<float*>(&v);
}

// tanh-form GELU via hardware exp; clamped so exp never overflows.
static __device__ __forceinline__ float gelu_fast(float z) {
    float zc = fminf(z, 8.0f);
    float u = 0.7978845608f * zc * (1.0f + 0.044715f * zc * zc);
    float w = __expf(2.0f * u);
    float t = (w - 1.0f) * __builtin_amdgcn_rcpf(w + 1.0f);
    return 0.5f * z * (1.0f + t);
}

// ---- standalone prep (fallback path only) ----
__global__ __launch_bounds__(256) void k_prep(const float* __restrict__ Vw2,
                                              ushort* __restrict__ Vw2t) {
    const int idx = (blockIdx.x * 256 + threadIdx.x) * 4;
    const int d = idx >> 7, k = idx & 127;
    ushort4 r;
    r.x = f2bf(Vw2[(size_t)(k + 0) * D_DIM + d]);
    r.y = f2bf(Vw2[(size_t)(k + 1) * D_DIM + d]);
    r.z = f2bf(Vw2[(size_t)(k + 2) * D_DIM + d]);
    r.w = f2bf(Vw2[(size_t)(k + 3) * D_DIM + d]);
    *reinterpret_cast<ushort4*>(Vw2t + d * HID + k) = r;
}

// ---- K1a: per-(bn, 64-token tile) partials + folded Vw2 transpose ----
__global__ __launch_bounds__(256, 8) void k_part(
    const float* __restrict__ x,      // [BN,T,D]
    const int* __restrict__ masks,    // [BN,T]
    const float* __restrict__ pos,    // [BN,T,3]
    const float* __restrict__ Vw2,    // [128,256]
    ushort* __restrict__ Vw2t,        // [256][128] bf16
    float* __restrict__ part_x,       // [BN,4,256]
    float* __restrict__ part_cp)      // [BN,4,4] (cnt,px,py,pz)
{
    __shared__ float s_part[4 * 256];

    const int bid = blockIdx.x;
    const int tid = threadIdx.x;

    if (bid >= BN_TOT * 4) {          // ---- folded k_prep ----
        const int pid = bid - BN_TOT * 4;
        const int idx = (pid * 256 + tid) * 4;
        const int d = idx >> 7, k = idx & 127;
        ushort4 r;
        r.x = f2bf(Vw2[(size_t)(k + 0) * D_DIM + d]);
        r.y = f2bf(Vw2[(size_t)(k + 1) * D_DIM + d]);
        r.z = f2bf(Vw2[(size_t)(k + 2) * D_DIM + d]);
        r.w = f2bf(Vw2[(size_t)(k + 3) * D_DIM + d]);
        *reinterpret_cast<ushort4*>(Vw2t + d * HID + k) = r;
        return;
    }

    const int bn = bid >> 2, tg = bid & 3;
    const int t0 = tg * 64;

    const float* xb = x + ((size_t)bn * T_DIM + t0) * D_DIM;
    const int*   mb = masks + bn * T_DIM + t0;

    {
        const int dq = tid & 63, tq = tid >> 6;   // wave == one tq
        float4 a = make_float4(0.f, 0.f, 0.f, 0.f);
        #pragma unroll
        for (int i = 0; i < 16; ++i) {
            const int t = tq * 16 + i;            // wave-uniform
            float m = (float)mb[t];
            float4 xv = *reinterpret_cast<const float4*>(xb + (size_t)t * D_DIM + dq * 4);
            a.x += m * xv.x; a.y += m * xv.y; a.z += m * xv.z; a.w += m * xv.w;
        }
        *reinterpret_cast<float4*>(s_part + tq * 256 + dq * 4) = a;
    }

    if (tid < 64) {
        float m = (float)mb[tid];
        const float* pp = pos + ((size_t)bn * T_DIM + t0 + tid) * 3;
        float c = m, px = m * pp[0], py = m * pp[1], pz = m * pp[2];
        #pragma unroll
        for (int off = 32; off > 0; off >>= 1) {
            c  += __shfl_down(c,  off, 64);
            px += __shfl_down(px, off, 64);
            py += __shfl_down(py, off, 64);
            pz += __shfl_down(pz, off, 64);
        }
        if (tid == 0)
            *reinterpret_cast<float4*>(part_cp + (bn * 4 + tg) * 4) =
                make_float4(c, px, py, pz);
    }
    __syncthreads();

    float s = s_part[tid] + s_part[256 + tid] + s_part[512 + tid] + s_part[768 + tid];
    part_x[((size_t)bn * 4 + tg) * 256 + tid] = s;
}

// ---- K1b: combine partials -> summary; v = summary @ Wv + bv + Vb2 ----
__global__ __launch_bounds__(256, 8) void k_v(
    const float* __restrict__ part_x,  // [BN,4,256]
    const float* __restrict__ part_cp, // [BN,4,4]
    const float* __restrict__ Wv,      // [D,D]
    const float* __restrict__ bv,
    const float* __restrict__ Vb2,
    float* __restrict__ v_ws,          // [BN,D]
    float* __restrict__ ps_ws)         // [BN,4]
{
    __shared__ float s_sum[256];
    __shared__ float s_part[4 * 256];
    __shared__ float s_cp[16];

    const int bn = blockIdx.x, tid = threadIdx.x;

    if (tid < 16) s_cp[tid] = part_cp[bn * 16 + tid];
    const float* pb = part_x + (size_t)bn * 1024;
    float s = pb[tid] + pb[256 + tid] + pb[512 + tid] + pb[768 + tid];
    __syncthreads();

    const float cnt = s_cp[0] + s_cp[4] + s_cp[8] + s_cp[12];
    const float inv = 1.0f / fmaxf(cnt, 1e-6f);
    s_sum[tid] = s * inv;
    if (tid < 3) {
        float p = s_cp[tid + 1] + s_cp[tid + 5] + s_cp[tid + 9] + s_cp[tid + 13];
        ps_ws[bn * 4 + tid] = p * inv;
    }
    __syncthreads();

    {
        const int dq = tid & 63, kq = tid >> 6;
        float4 a = make_float4(0.f, 0.f, 0.f, 0.f);
        #pragma unroll 8
        for (int i = 0; i < 64; ++i) {
            const int k = kq * 64 + i;
            float sc = s_sum[k];
            float4 w = *reinterpret_cast<const float4*>(Wv + (size_t)k * D_DIM + dq * 4);
            a.x += sc * w.x; a.y += sc * w.y; a.z += sc * w.z; a.w += sc * w.w;
        }
        *reinterpret_cast<float4*>(s_part + kq * 256 + dq * 4) = a;
    }
    __syncthreads();
    v_ws[bn * D_DIM + tid] = s_part[tid] + s_part[256 + tid] + s_part[512 + tid] +
                             s_part[768 + tid] + bv[tid] + Vb2[tid];
}

// ---- fallback K1 (r4-proven single-kernel summary) ----
__global__ __launch_bounds__(512, 8) void k_sum(
    const float* __restrict__ x, const int* __restrict__ masks,
    const float* __restrict__ pos, const float* __restrict__ Wv,
    const float* __restrict__ bv, const float* __restrict__ Vb2,
    float* __restrict__ v_ws, float* __restrict__ ps_ws)
{
    __shared__ float s_m[256];
    __shared__ float s_red[4 * 256];
    __shared__ float s_part[8 * 256];
    __shared__ float s_sum[256];

    const int bn = blockIdx.x, tid = threadIdx.x;
    const float* xb = x + (size_t)bn * T_DIM * D_DIM;

    if (tid < 256) {
        float m = (float)masks[bn * T_DIM + tid];
        s_m[tid] = m;
        const float* pp = pos + ((size_t)bn * T_DIM + tid) * 3;
        s_red[0 * 256 + tid] = m;
        s_red[1 * 256 + tid] = m * pp[0];
        s_red[2 * 256 + tid] = m * pp[1];
        s_red[3 * 256 + tid] = m * pp[2];
    }
    __syncthreads();
    {
        const int dq = tid & 63, tq = tid >> 6;
        float4 a = make_float4(0.f, 0.f, 0.f, 0.f);
        const float* px = xb + (size_t)tq * 32 * D_DIM + dq * 4;
        #pragma unroll 8
        for (int i = 0; i < 32; ++i) {
            float m = s_m[tq * 32 + i];
            float4 xv = *reinterpret_cast<const float4*>(px + i * D_DIM);
            a.x += m * xv.x; a.y += m * xv.y; a.z += m * xv.z; a.w += m * xv.w;
        }
        *reinterpret_cast<float4*>(s_part + tq * 256 + dq * 4) = a;
    }
    __syncthreads();
    for (int off = 128; off > 0; off >>= 1) {
        if (tid < off) {
            s_red[0 * 256 + tid] += s_red[0 * 256 + tid + off];
            s_red[1 * 256 + tid] += s_red[1 * 256 + tid + off];
            s_red[2 * 256 + tid] += s_red[2 * 256 + tid + off];
            s_red[3 * 256 + tid] += s_red[3 * 256 + tid + off];
        }
        __syncthreads();
    }
    const float inv = 1.0f / fmaxf(s_red[0], 1e-6f);
    if (tid < 3) ps_ws[bn * 4 + tid] = s_red[(tid + 1) * 256] * inv;
    if (tid < 256) {
        float s = 0.f;
        #pragma unroll
        for (int q = 0; q < 8; ++q) s += s_part[q * 256 + tid];
        s_sum[tid] = s * inv;
    }
    __syncthreads();
    {
        const int dq = tid & 63, kq = tid >> 6;
        float4 a = make_float4(0.f, 0.f, 0.f, 0.f);
        #pragma unroll 8
        for (int i = 0; i < 32; ++i) {
            const int k = kq * 32 + i;
            float sc = s_sum[k];
            float4 w = *reinterpret_cast<const float4*>(Wv + (size_t)k * D_DIM + dq * 4);
            a.x += sc * w.x; a.y += sc * w.y; a.z += sc * w.z; a.w += sc * w.w;
        }
        *reinterpret_cast<float4*>(s_part + kq * 256 + dq * 4) = a;
    }
    __syncthreads();
    if (tid < 256) {
        float r = bv[tid] + Vb2[tid];
        #pragma unroll
        for (int q = 0; q < 8; ++q) r += s_part[q * 256 + tid];
        v_ws[bn * D_DIM + tid] = r;
    }
}

// ---- K2: fused MLP + two-pass MFMA GEMM + bf16-tile row epilogue ----
// grid 4096: block -> (bn = b>>3, 32-token tile b&7); 256 thr (4 waves).
// LDS: s_hid 8KB | s_tile 16KB (separate) + rf -> ~25KB -> 6 blocks/CU.
// Each m-pass keeps wfr[4]-upfront ILP with only acc[1][4] live.
__global__ __launch_bounds__(256, 6) void k_fused(
    const float* __restrict__ x,
    const float* __restrict__ pos,
    const float* __restrict__ Vw1,    // [5,128]
    const float* __restrict__ Vb1,    // [128]
    const ushort* __restrict__ Vw2t,  // [256][128] bf16
    const float* __restrict__ v_ws,   // [BN,256] (= v + bv + Vb2)
    const float* __restrict__ ps_ws,  // [BN,4]
    float* __restrict__ out)
{
    __shared__ __align__(16) char s_hid[8 * 1024];    // bf16 hidden, swizzled
    __shared__ __align__(16) char s_tile[16 * 1024];  // bf16 rel_val tile
    __shared__ float s_rf[32 * 6];

    const int bt  = blockIdx.x;
    const int bn  = bt >> 3;
    const int t0  = (bt & 7) * 32;
    const int tid = threadIdx.x;
    const int l   = tid & 63;
    const int wc  = tid >> 6;           // d quarter (64 cols)
    const int lrow = l & 15;
    const int lk   = l >> 4;            // k-slice lane (0..3)

    // ---- rel features for this 32-token tile ----
    const float psx = ps_ws[bn * 4 + 0];
    const float psy = ps_ws[bn * 4 + 1];
    const float psz = ps_ws[bn * 4 + 2];
    if (tid < 32) {
        const float* pp = pos + ((size_t)bn * T_DIM + t0 + tid) * 3;
        float dx = pp[0] - psx, dy = pp[1] - psy, dz = pp[2] - psz;
        float d2 = dx * dx + dy * dy + dz * dz;
        s_rf[tid * 6 + 0] = dx; s_rf[tid * 6 + 1] = dy; s_rf[tid * 6 + 2] = dz;
        s_rf[tid * 6 + 3] = sqrtf(d2); s_rf[tid * 6 + 4] = d2;
    }
    __syncthreads();

    // ---- hidden = gelu(rf @ Vw1 + Vb1) -> s_hid bf16, swizzled (verified)
    {
        const int cg = tid & 31, c0 = cg * 4;
        const float4 w0 = *reinterpret_cast<const float4*>(Vw1 + 0 * HID + c0);
        const float4 w1 = *reinterpret_cast<const float4*>(Vw1 + 1 * HID + c0);
        const float4 w2 = *reinterpret_cast<const float4*>(Vw1 + 2 * HID + c0);
        const float4 w3 = *reinterpret_cast<const float4*>(Vw1 + 3 * HID + c0);
        const float4 w4 = *reinterpret_cast<const float4*>(Vw1 + 4 * HID + c0);
        const float4 bb = *reinterpret_cast<const float4*>(Vb1 + c0);
        const int tok0 = (tid >> 5) * 4;
        #pragma unroll
        for (int s = 0; s < 4; ++s) {
            const int tok = tok0 + s;
            const float* rf = s_rf + tok * 6;
            const float dx = rf[0], dy = rf[1], dz = rf[2], dd = rf[3], d2 = rf[4];
            float z0 = bb.x + dx * w0.x + dy * w1.x + dz * w2.x + dd * w3.x + d2 * w4.x;
            float z1 = bb.y + dx * w0.y + dy * w1.y + dz * w2.y + dd * w3.y + d2 * w4.y;
            float z2 = bb.z + dx * w0.z + dy * w1.z + dz * w2.z + dd * w3.z + d2 * w4.z;
            float z3 = bb.w + dx * w0.w + dy * w1.w + dz * w2.w + dd * w3.w + d2 * w4.w;
            uint p0 = (uint)f2bf(gelu_fast(z0)) | ((uint)f2bf(gelu_fast(z1)) << 16);
            uint p1 = (uint)f2bf(gelu_fast(z2)) | ((uint)f2bf(gelu_fast(z3)) << 16);
            int byte = tok * 256 + cg * 8;
            byte ^= (tok & 15) << 4;
            *reinterpret_cast<uint2*>(s_hid + byte) = make_uint2(p0, p1);
        }
    }
    __syncthreads();

    // ---- GEMM (operand-swapped): two m-passes, wfr[4]-upfront ILP each
    const ushort* wb = Vw2t + (size_t)(wc * 64 + lrow) * HID + lk * 8;
    const int koff16 = lk * 16;

    #pragma unroll
    for (int m = 0; m < 2; ++m) {
        f32x4 acc[4];
        #pragma unroll
        for (int n = 0; n < 4; ++n) acc[n] = (f32x4){0.f, 0.f, 0.f, 0.f};
        const int tok = m * 16 + lrow;

        #pragma unroll
        for (int ks = 0; ks < 4; ++ks) {
            short8v wfr[4];
            #pragma unroll
            for (int n = 0; n < 4; ++n)
                wfr[n] = *reinterpret_cast<const short8v*>(wb + n * 16 * HID + ks * 32);
            int byte = tok * 256 + ks * 64 + koff16;
            byte ^= (tok & 15) << 4;
            short8v hfr = *reinterpret_cast<const short8v*>(s_hid + byte);
            #pragma unroll
            for (int n = 0; n < 4; ++n)
                acc[n] = __builtin_amdgcn_mfma_f32_16x16x32_bf16(
                    wfr[n], hfr, acc[n], 0, 0, 0);
        }

        // write this pass's 16 tile rows (separate region from s_hid -> safe)
        #pragma unroll
        for (int n = 0; n < 4; ++n) {
            const int d0 = wc * 64 + n * 16 + lk * 4;
            ushort4 b;
            b.x = f2bf(acc[n][0]); b.y = f2bf(acc[n][1]);
            b.z = f2bf(acc[n][2]); b.w = f2bf(acc[n][3]);
            int byte = tok * 512 + d0 * 2;
            byte ^= (tok & 15) << 3;
            *reinterpret_cast<ushort4*>(s_tile + byte) = b;
        }
    }
    __syncthreads();

    // ---- row-contiguous epilogue: out = x + vb + rel_val
    const int l4 = l * 4;
    const f32x4 vbl = *reinterpret_cast<const f32x4*>(v_ws + bn * D_DIM + l4);
    const float* xb = x + ((size_t)bn * T_DIM + t0) * D_DIM;
    float*       ob = out + ((size_t)bn * T_DIM + t0) * D_DIM;

    #pragma unroll
    for (int i = 0; i < 8; ++i) {
        const int r = wc * 8 + i;             // wave owns rows wc*8..wc*8+7
        f32x4 xv = *reinterpret_cast<const f32x4*>(xb + (size_t)r * D_DIM + l4);
        int byte = r * 512 + l * 8;
        byte ^= (r & 15) << 3;
        ushort4 tb = *reinterpret_cast<const ushort4*>(s_tile + byte);
        f32x4 o;
        o[0] = xv[0] + vbl[0] + bf2f(tb.x);
        o[1] = xv[1] + vbl[1] + bf2f(tb.y);
        o[2] = xv[2] + vbl[2] + bf2f(tb.z);
        o[3] = xv[3] + vbl[3] + bf2f(tb.w);
        *reinterpret_cast<f32x4*>(ob + (size_t)r * D_DIM + l4) = o;
    }
}

extern "C" void kernel_launch(void* const* d_in, const int* in_sizes, int n_in,
                              void* d_out, int out_size, void* d_ws, size_t ws_size,
                              hipStream_t stream) {
    const float* x     = (const float*)d_in[0];
    // d_in[1] = sum_token (unused by reference)
    const int*   masks = (const int*)d_in[2];
    const float* pos   = (const float*)d_in[3];
    // d_in[4..7] = Wq,bq,Wk,bk (dead: softmax over size-1 axis == 1)
    const float* Wv    = (const float*)d_in[8];
    const float* bv    = (const float*)d_in[9];
    // d_in[10..13] = bias-MLP (dead)
    const float* Vw1   = (const float*)d_in[14];
    const float* Vb1   = (const float*)d_in[15];
    const float* Vw2   = (const float*)d_in[16];
    const float* Vb2   = (const float*)d_in[17];
    float* out = (float*)d_out;

    // ws layout: Vw2t 64KB | v 512KB | ps 8KB | part_x 2MB | part_cp 32KB
    ushort* Vw2t  = (ushort*)d_ws;
    float*  v_ws  = (float*)(Vw2t + D_DIM * HID);
    float*  ps_ws = v_ws + BN_TOT * D_DIM;
    float*  part_x  = ps_ws + BN_TOT * 4;
    float*  part_cp = part_x + (size_t)BN_TOT * 4 * 256;
    const size_t need_split = (size_t)((char*)(part_cp + BN_TOT * 16) - (char*)d_ws);

    if (ws_size >= need_split) {
        // k_prep folded into k_part's tail blocks
        k_part<<<BN_TOT * 4 + 32, 256, 0, stream>>>(x, masks, pos, Vw2, Vw2t,
                                                    part_x, part_cp);
        k_v<<<BN_TOT, 256, 0, stream>>>(part_x, part_cp, Wv, bv, Vb2, v_ws, ps_ws);
    } else {
        k_prep<<<32, 256, 0, stream>>>(Vw2, Vw2t);
        k_sum<<<BN_TOT, 512, 0, stream>>>(x, masks, pos, Wv, bv, Vb2, v_ws, ps_ws);
    }
    k_fused<<<BN_TOT * 8, 256, 0, stream>>>(x, pos, Vw1, Vb1, Vw2t,
                                            v_ws, ps_ws, out);
}

// Round 17
// 85.956 us; speedup vs baseline: 1.3038x; 1.3038x over previous
//
#include <hip/hip_runtime.h>
#include <hip/hip_bf16.h>
#include <math.h>

// Collapsed math (softmax over the size-1 summary axis == 1 identically, so
// q/Wq/Wk/bias-MLP/mask-bias are dead code):
//   summary[bn,:] = sum_t m*x / max(sum_t m, 1e-6)
//   v[bn,:]       = summary @ Wv + bv
//   rf[bn,t]      = [dx,dy,dz,||d||,||d||^2] vs masked-mean position
//   rel_val       = gelu(rf @ Vw1 + Vb1) @ Vw2 + Vb2   (bf16 MFMA)
//   out[bn,t,:]   = x[bn,t,:] + v[bn,:] + rel_val[bn,t,:]
//
// Round-17: REVERT to the r15 structure (87.9us, best verified). r16's
// two-pass GEMM (halved acc) serialized the MFMA pipeline (4 indep chains,
// tile-write fence mid-GEMM) -> k_fused 60->90us. Third confirmation that
// TLP cannot repay lost ILP on this kernel. r15 = ILP-rich wfr[4]-upfront
// loop + bf16 union tile (17KB LDS) + lb(256,5) + folded prep.

#define BN_TOT 512
#define T_DIM 256
#define D_DIM 256
#define HID 128

typedef __attribute__((ext_vector_type(8))) short short8v;
typedef __attribute__((ext_vector_type(4))) float f32x4;

static __device__ __forceinline__ ushort f2bf(float f) {
    __hip_bfloat16 h = __float2bfloat16(f);
    return *reinterpret_cast<ushort*>(&h);
}
static __device__ __forceinline__ float bf2f(ushort u) {
    uint v = ((uint)u) << 16;
    return *reinterpret_cast<float*>(&v);
}

// tanh-form GELU via hardware exp; clamped so exp never overflows.
static __device__ __forceinline__ float gelu_fast(float z) {
    float zc = fminf(z, 8.0f);
    float u = 0.7978845608f * zc * (1.0f + 0.044715f * zc * zc);
    float w = __expf(2.0f * u);
    float t = (w - 1.0f) * __builtin_amdgcn_rcpf(w + 1.0f);
    return 0.5f * z * (1.0f + t);
}

// ---- standalone prep (fallback path only) ----
__global__ __launch_bounds__(256) void k_prep(const float* __restrict__ Vw2,
                                              ushort* __restrict__ Vw2t) {
    const int idx = (blockIdx.x * 256 + threadIdx.x) * 4;
    const int d = idx >> 7, k = idx & 127;
    ushort4 r;
    r.x = f2bf(Vw2[(size_t)(k + 0) * D_DIM + d]);
    r.y = f2bf(Vw2[(size_t)(k + 1) * D_DIM + d]);
    r.z = f2bf(Vw2[(size_t)(k + 2) * D_DIM + d]);
    r.w = f2bf(Vw2[(size_t)(k + 3) * D_DIM + d]);
    *reinterpret_cast<ushort4*>(Vw2t + d * HID + k) = r;
}

// ---- K1a: per-(bn, 64-token tile) partials + folded Vw2 transpose ----
// grid 2048+32: bid<2048 -> partials; bid>=2048 -> transpose chunk.
__global__ __launch_bounds__(256, 8) void k_part(
    const float* __restrict__ x,      // [BN,T,D]
    const int* __restrict__ masks,    // [BN,T]
    const float* __restrict__ pos,    // [BN,T,3]
    const float* __restrict__ Vw2,    // [128,256]
    ushort* __restrict__ Vw2t,        // [256][128] bf16
    float* __restrict__ part_x,       // [BN,4,256]
    float* __restrict__ part_cp)      // [BN,4,4] (cnt,px,py,pz)
{
    __shared__ float s_part[4 * 256];

    const int bid = blockIdx.x;
    const int tid = threadIdx.x;

    if (bid >= BN_TOT * 4) {          // ---- folded k_prep ----
        const int pid = bid - BN_TOT * 4;
        const int idx = (pid * 256 + tid) * 4;
        const int d = idx >> 7, k = idx & 127;
        ushort4 r;
        r.x = f2bf(Vw2[(size_t)(k + 0) * D_DIM + d]);
        r.y = f2bf(Vw2[(size_t)(k + 1) * D_DIM + d]);
        r.z = f2bf(Vw2[(size_t)(k + 2) * D_DIM + d]);
        r.w = f2bf(Vw2[(size_t)(k + 3) * D_DIM + d]);
        *reinterpret_cast<ushort4*>(Vw2t + d * HID + k) = r;
        return;
    }

    const int bn = bid >> 2, tg = bid & 3;
    const int t0 = tg * 64;

    const float* xb = x + ((size_t)bn * T_DIM + t0) * D_DIM;
    const int*   mb = masks + bn * T_DIM + t0;

    {
        const int dq = tid & 63, tq = tid >> 6;   // wave == one tq
        float4 a = make_float4(0.f, 0.f, 0.f, 0.f);
        #pragma unroll
        for (int i = 0; i < 16; ++i) {
            const int t = tq * 16 + i;            // wave-uniform
            float m = (float)mb[t];
            float4 xv = *reinterpret_cast<const float4*>(xb + (size_t)t * D_DIM + dq * 4);
            a.x += m * xv.x; a.y += m * xv.y; a.z += m * xv.z; a.w += m * xv.w;
        }
        *reinterpret_cast<float4*>(s_part + tq * 256 + dq * 4) = a;
    }

    if (tid < 64) {
        float m = (float)mb[tid];
        const float* pp = pos + ((size_t)bn * T_DIM + t0 + tid) * 3;
        float c = m, px = m * pp[0], py = m * pp[1], pz = m * pp[2];
        #pragma unroll
        for (int off = 32; off > 0; off >>= 1) {
            c  += __shfl_down(c,  off, 64);
            px += __shfl_down(px, off, 64);
            py += __shfl_down(py, off, 64);
            pz += __shfl_down(pz, off, 64);
        }
        if (tid == 0)
            *reinterpret_cast<float4*>(part_cp + (bn * 4 + tg) * 4) =
                make_float4(c, px, py, pz);
    }
    __syncthreads();

    float s = s_part[tid] + s_part[256 + tid] + s_part[512 + tid] + s_part[768 + tid];
    part_x[((size_t)bn * 4 + tg) * 256 + tid] = s;
}

// ---- K1b: combine partials -> summary; v = summary @ Wv + bv + Vb2 ----
__global__ __launch_bounds__(256, 8) void k_v(
    const float* __restrict__ part_x,  // [BN,4,256]
    const float* __restrict__ part_cp, // [BN,4,4]
    const float* __restrict__ Wv,      // [D,D]
    const float* __restrict__ bv,
    const float* __restrict__ Vb2,
    float* __restrict__ v_ws,          // [BN,D]
    float* __restrict__ ps_ws)         // [BN,4]
{
    __shared__ float s_sum[256];
    __shared__ float s_part[4 * 256];
    __shared__ float s_cp[16];

    const int bn = blockIdx.x, tid = threadIdx.x;

    if (tid < 16) s_cp[tid] = part_cp[bn * 16 + tid];
    const float* pb = part_x + (size_t)bn * 1024;
    float s = pb[tid] + pb[256 + tid] + pb[512 + tid] + pb[768 + tid];
    __syncthreads();

    const float cnt = s_cp[0] + s_cp[4] + s_cp[8] + s_cp[12];
    const float inv = 1.0f / fmaxf(cnt, 1e-6f);
    s_sum[tid] = s * inv;
    if (tid < 3) {
        float p = s_cp[tid + 1] + s_cp[tid + 5] + s_cp[tid + 9] + s_cp[tid + 13];
        ps_ws[bn * 4 + tid] = p * inv;
    }
    __syncthreads();

    {
        const int dq = tid & 63, kq = tid >> 6;
        float4 a = make_float4(0.f, 0.f, 0.f, 0.f);
        #pragma unroll 8
        for (int i = 0; i < 64; ++i) {
            const int k = kq * 64 + i;
            float sc = s_sum[k];
            float4 w = *reinterpret_cast<const float4*>(Wv + (size_t)k * D_DIM + dq * 4);
            a.x += sc * w.x; a.y += sc * w.y; a.z += sc * w.z; a.w += sc * w.w;
        }
        *reinterpret_cast<float4*>(s_part + kq * 256 + dq * 4) = a;
    }
    __syncthreads();
    v_ws[bn * D_DIM + tid] = s_part[tid] + s_part[256 + tid] + s_part[512 + tid] +
                             s_part[768 + tid] + bv[tid] + Vb2[tid];
}

// ---- fallback K1 (r4-proven single-kernel summary) ----
__global__ __launch_bounds__(512, 8) void k_sum(
    const float* __restrict__ x, const int* __restrict__ masks,
    const float* __restrict__ pos, const float* __restrict__ Wv,
    const float* __restrict__ bv, const float* __restrict__ Vb2,
    float* __restrict__ v_ws, float* __restrict__ ps_ws)
{
    __shared__ float s_m[256];
    __shared__ float s_red[4 * 256];
    __shared__ float s_part[8 * 256];
    __shared__ float s_sum[256];

    const int bn = blockIdx.x, tid = threadIdx.x;
    const float* xb = x + (size_t)bn * T_DIM * D_DIM;

    if (tid < 256) {
        float m = (float)masks[bn * T_DIM + tid];
        s_m[tid] = m;
        const float* pp = pos + ((size_t)bn * T_DIM + tid) * 3;
        s_red[0 * 256 + tid] = m;
        s_red[1 * 256 + tid] = m * pp[0];
        s_red[2 * 256 + tid] = m * pp[1];
        s_red[3 * 256 + tid] = m * pp[2];
    }
    __syncthreads();
    {
        const int dq = tid & 63, tq = tid >> 6;
        float4 a = make_float4(0.f, 0.f, 0.f, 0.f);
        const float* px = xb + (size_t)tq * 32 * D_DIM + dq * 4;
        #pragma unroll 8
        for (int i = 0; i < 32; ++i) {
            float m = s_m[tq * 32 + i];
            float4 xv = *reinterpret_cast<const float4*>(px + i * D_DIM);
            a.x += m * xv.x; a.y += m * xv.y; a.z += m * xv.z; a.w += m * xv.w;
        }
        *reinterpret_cast<float4*>(s_part + tq * 256 + dq * 4) = a;
    }
    __syncthreads();
    for (int off = 128; off > 0; off >>= 1) {
        if (tid < off) {
            s_red[0 * 256 + tid] += s_red[0 * 256 + tid + off];
            s_red[1 * 256 + tid] += s_red[1 * 256 + tid + off];
            s_red[2 * 256 + tid] += s_red[2 * 256 + tid + off];
            s_red[3 * 256 + tid] += s_red[3 * 256 + tid + off];
        }
        __syncthreads();
    }
    const float inv = 1.0f / fmaxf(s_red[0], 1e-6f);
    if (tid < 3) ps_ws[bn * 4 + tid] = s_red[(tid + 1) * 256] * inv;
    if (tid < 256) {
        float s = 0.f;
        #pragma unroll
        for (int q = 0; q < 8; ++q) s += s_part[q * 256 + tid];
        s_sum[tid] = s * inv;
    }
    __syncthreads();
    {
        const int dq = tid & 63, kq = tid >> 6;
        float4 a = make_float4(0.f, 0.f, 0.f, 0.f);
        #pragma unroll 8
        for (int i = 0; i < 32; ++i) {
            const int k = kq * 32 + i;
            float sc = s_sum[k];
            float4 w = *reinterpret_cast<const float4*>(Wv + (size_t)k * D_DIM + dq * 4);
            a.x += sc * w.x; a.y += sc * w.y; a.z += sc * w.z; a.w += sc * w.w;
        }
        *reinterpret_cast<float4*>(s_part + kq * 256 + dq * 4) = a;
    }
    __syncthreads();
    if (tid < 256) {
        float r = bv[tid] + Vb2[tid];
        #pragma unroll
        for (int q = 0; q < 8; ++q) r += s_part[q * 256 + tid];
        v_ws[bn * D_DIM + tid] = r;
    }
}

// ---- K2: fused MLP + ILP-rich MFMA GEMM + bf16-tile row epilogue ----
// grid 4096: block -> (bn = b>>3, 32-token tile b&7); 256 thr (4 waves).
// Union LDS region: s_hid 8KB / s_tile 16KB -> 16KB + rf; lb(256,5):
// budget 102 regs >= live ~85 (incl. 32-AGPR acc) -> no spill, 5 blocks/CU.
__global__ __launch_bounds__(256, 5) void k_fused(
    const float* __restrict__ x,
    const float* __restrict__ pos,
    const float* __restrict__ Vw1,    // [5,128]
    const float* __restrict__ Vb1,    // [128]
    const ushort* __restrict__ Vw2t,  // [256][128] bf16
    const float* __restrict__ v_ws,   // [BN,256] (= v + bv + Vb2)
    const float* __restrict__ ps_ws,  // [BN,4]
    float* __restrict__ out)
{
    __shared__ __align__(16) char s_mem[16 * 1024];   // union: s_hid / s_tile
    __shared__ float s_rf[32 * 6];

    const int bt  = blockIdx.x;
    const int bn  = bt >> 3;
    const int t0  = (bt & 7) * 32;
    const int tid = threadIdx.x;
    const int l   = tid & 63;
    const int wc  = tid >> 6;           // d quarter (64 cols)
    const int lrow = l & 15;
    const int lk   = l >> 4;            // k-slice lane (0..3)

    // ---- rel features for this 32-token tile ----
    const float psx = ps_ws[bn * 4 + 0];
    const float psy = ps_ws[bn * 4 + 1];
    const float psz = ps_ws[bn * 4 + 2];
    if (tid < 32) {
        const float* pp = pos + ((size_t)bn * T_DIM + t0 + tid) * 3;
        float dx = pp[0] - psx, dy = pp[1] - psy, dz = pp[2] - psz;
        float d2 = dx * dx + dy * dy + dz * dz;
        s_rf[tid * 6 + 0] = dx; s_rf[tid * 6 + 1] = dy; s_rf[tid * 6 + 2] = dz;
        s_rf[tid * 6 + 3] = sqrtf(d2); s_rf[tid * 6 + 4] = d2;
    }
    __syncthreads();

    // ---- hidden = gelu(rf @ Vw1 + Vb1) -> s_hid bf16, swizzled (verified)
    {
        const int cg = tid & 31, c0 = cg * 4;
        const float4 w0 = *reinterpret_cast<const float4*>(Vw1 + 0 * HID + c0);
        const float4 w1 = *reinterpret_cast<const float4*>(Vw1 + 1 * HID + c0);
        const float4 w2 = *reinterpret_cast<const float4*>(Vw1 + 2 * HID + c0);
        const float4 w3 = *reinterpret_cast<const float4*>(Vw1 + 3 * HID + c0);
        const float4 w4 = *reinterpret_cast<const float4*>(Vw1 + 4 * HID + c0);
        const float4 bb = *reinterpret_cast<const float4*>(Vb1 + c0);
        const int tok0 = (tid >> 5) * 4;
        #pragma unroll
        for (int s = 0; s < 4; ++s) {
            const int tok = tok0 + s;
            const float* rf = s_rf + tok * 6;
            const float dx = rf[0], dy = rf[1], dz = rf[2], dd = rf[3], d2 = rf[4];
            float z0 = bb.x + dx * w0.x + dy * w1.x + dz * w2.x + dd * w3.x + d2 * w4.x;
            float z1 = bb.y + dx * w0.y + dy * w1.y + dz * w2.y + dd * w3.y + d2 * w4.y;
            float z2 = bb.z + dx * w0.z + dy * w1.z + dz * w2.z + dd * w3.z + d2 * w4.z;
            float z3 = bb.w + dx * w0.w + dy * w1.w + dz * w2.w + dd * w3.w + d2 * w4.w;
            uint p0 = (uint)f2bf(gelu_fast(z0)) | ((uint)f2bf(gelu_fast(z1)) << 16);
            uint p1 = (uint)f2bf(gelu_fast(z2)) | ((uint)f2bf(gelu_fast(z3)) << 16);
            int byte = tok * 256 + cg * 8;
            byte ^= (tok & 15) << 4;
            *reinterpret_cast<uint2*>(s_mem + byte) = make_uint2(p0, p1);
        }
    }
    __syncthreads();

    // ---- GEMM (operand-swapped, ILP-rich r12 loop): D = Wfrag @ hidfrag
    f32x4 acc[2][4];
    #pragma unroll
    for (int m = 0; m < 2; ++m)
        #pragma unroll
        for (int n = 0; n < 4; ++n) acc[m][n] = (f32x4){0.f, 0.f, 0.f, 0.f};

    const ushort* wb = Vw2t + (size_t)(wc * 64 + lrow) * HID + lk * 8;
    const int koff16 = lk * 16;

    #pragma unroll
    for (int ks = 0; ks < 4; ++ks) {
        short8v wfr[4];
        #pragma unroll
        for (int n = 0; n < 4; ++n)
            wfr[n] = *reinterpret_cast<const short8v*>(wb + n * 16 * HID + ks * 32);
        short8v hfr[2];
        #pragma unroll
        for (int m = 0; m < 2; ++m) {
            const int tok = m * 16 + lrow;
            int byte = tok * 256 + ks * 64 + koff16;
            byte ^= (tok & 15) << 4;
            hfr[m] = *reinterpret_cast<const short8v*>(s_mem + byte);
        }
        #pragma unroll
        for (int m = 0; m < 2; ++m)
            #pragma unroll
            for (int n = 0; n < 4; ++n)
                acc[m][n] = __builtin_amdgcn_mfma_f32_16x16x32_bf16(
                    wfr[n], hfr[m], acc[m][n], 0, 0, 0);
    }
    __syncthreads();   // all s_hid reads complete before s_tile overwrites

    // ---- acc -> s_tile [32 tok][256 d] bf16, swizzled ((tok&15)<<3 on 8B)
    #pragma unroll
    for (int m = 0; m < 2; ++m) {
        const int tok = m * 16 + lrow;
        #pragma unroll
        for (int n = 0; n < 4; ++n) {
            const int d0 = wc * 64 + n * 16 + lk * 4;
            ushort4 b;
            b.x = f2bf(acc[m][n][0]); b.y = f2bf(acc[m][n][1]);
            b.z = f2bf(acc[m][n][2]); b.w = f2bf(acc[m][n][3]);
            int byte = tok * 512 + d0 * 2;
            byte ^= (tok & 15) << 3;
            *reinterpret_cast<ushort4*>(s_mem + byte) = b;
        }
    }
    __syncthreads();

    // ---- row-contiguous epilogue: out = x + vb + rel_val
    const int l4 = l * 4;
    const f32x4 vbl = *reinterpret_cast<const f32x4*>(v_ws + bn * D_DIM + l4);
    const float* xb = x + ((size_t)bn * T_DIM + t0) * D_DIM;
    float*       ob = out + ((size_t)bn * T_DIM + t0) * D_DIM;

    #pragma unroll
    for (int i = 0; i < 8; ++i) {
        const int r = wc * 8 + i;             // wave owns rows wc*8..wc*8+7
        f32x4 xv = *reinterpret_cast<const f32x4*>(xb + (size_t)r * D_DIM + l4);
        int byte = r * 512 + l * 8;
        byte ^= (r & 15) << 3;
        ushort4 tb = *reinterpret_cast<const ushort4*>(s_mem + byte);
        f32x4 o;
        o[0] = xv[0] + vbl[0] + bf2f(tb.x);
        o[1] = xv[1] + vbl[1] + bf2f(tb.y);
        o[2] = xv[2] + vbl[2] + bf2f(tb.z);
        o[3] = xv[3] + vbl[3] + bf2f(tb.w);
        *reinterpret_cast<f32x4*>(ob + (size_t)r * D_DIM + l4) = o;
    }
}

extern "C" void kernel_launch(void* const* d_in, const int* in_sizes, int n_in,
                              void* d_out, int out_size, void* d_ws, size_t ws_size,
                              hipStream_t stream) {
    const float* x     = (const float*)d_in[0];
    // d_in[1] = sum_token (unused by reference)
    const int*   masks = (const int*)d_in[2];
    const float* pos   = (const float*)d_in[3];
    // d_in[4..7] = Wq,bq,Wk,bk (dead: softmax over size-1 axis == 1)
    const float* Wv    = (const float*)d_in[8];
    const float* bv    = (const float*)d_in[9];
    // d_in[10..13] = bias-MLP (dead)
    const float* Vw1   = (const float*)d_in[14];
    const float* Vb1   = (const float*)d_in[15];
    const float* Vw2   = (const float*)d_in[16];
    const float* Vb2   = (const float*)d_in[17];
    float* out = (float*)d_out;

    // ws layout: Vw2t 64KB | v 512KB | ps 8KB | part_x 2MB | part_cp 32KB
    ushort* Vw2t  = (ushort*)d_ws;
    float*  v_ws  = (float*)(Vw2t + D_DIM * HID);
    float*  ps_ws = v_ws + BN_TOT * D_DIM;
    float*  part_x  = ps_ws + BN_TOT * 4;
    float*  part_cp = part_x + (size_t)BN_TOT * 4 * 256;
    const size_t need_split = (size_t)((char*)(part_cp + BN_TOT * 16) - (char*)d_ws);

    if (ws_size >= need_split) {
        // k_prep folded into k_part's tail blocks
        k_part<<<BN_TOT * 4 + 32, 256, 0, stream>>>(x, masks, pos, Vw2, Vw2t,
                                                    part_x, part_cp);
        k_v<<<BN_TOT, 256, 0, stream>>>(part_x, part_cp, Wv, bv, Vb2, v_ws, ps_ws);
    } else {
        k_prep<<<32, 256, 0, stream>>>(Vw2, Vw2t);
        k_sum<<<BN_TOT, 512, 0, stream>>>(x, masks, pos, Wv, bv, Vb2, v_ws, ps_ws);
    }
    k_fused<<<BN_TOT * 8, 256, 0, stream>>>(x, pos, Vw1, Vb1, Vw2t,
                                            v_ws, ps_ws, out);
}